// Round 11
// baseline (364.015 us; speedup 1.0000x reference)
//
#include <hip/hip_runtime.h>
#include <hip/hip_fp16.h>

// ---------------------------------------------------------------------------
// VGAE encoder: two GCN propagations + dense transforms.
// Transform-first: t = x@W1, h = relu(agg(t)+b1), g = h@[Wmu|Wlv],
// [mu|lv] = agg(g)+bias  (agg commutes with the right-multiply).
// Features live in TWO 64-col fp16 slabs ([n][64], 128B row = 1 cache line).
// Each agg runs as two sequential 64-col launches so the gather working set
// is 12.8MB (vs 25.6) -> higher L2 hit rate at unchanged line-request
// efficiency (32B-granular chunking previously lost 3x on request rate).
// Per instruction: two 32-lane groups gather two different edges' rows;
// cross-half shfl_xor(32) reduction at the end.
// CSR build: bucket-count -> scan -> partition (packed uint32 pairs,
// s|dlow<<24) -> fused build. All scatter windows L2-local.
// ---------------------------------------------------------------------------

using half8 = __attribute__((ext_vector_type(8))) _Float16;
using f32x4 = __attribute__((ext_vector_type(4))) float;
using f32x2 = __attribute__((ext_vector_type(2))) float;

// Detect whether edge_index arrived as int64 (odd int32 words all zero) or
// int32. Wave-parallel. Writes mode=1 for int64, 0 for int32.
__global__ void detect_kernel(const int* __restrict__ ei, int* __restrict__ mode) {
    int lane = threadIdx.x & 63;
    int any = 0;
    for (int k = lane; k < 1024; k += 64) any |= ei[2 * k + 1];
    unsigned long long b = __ballot(any != 0);
    if (threadIdx.x == 0) *mode = (b == 0ull) ? 1 : 0;
}

// Count edges per 256-node dst bucket (K buckets) via LDS histogram.
// Validity predicate MUST match partition_kernel exactly.
__global__ __launch_bounds__(256) void bucket_count_kernel(
    const int* __restrict__ ei, int E, int n, const int* __restrict__ mode,
    int* __restrict__ bcnt) {
    __shared__ int h[512];
    int t = threadIdx.x;
    for (int i = t; i < 512; i += 256) h[i] = 0;
    __syncthreads();
    int m = *mode;
    int e0 = blockIdx.x * 4096;
#pragma unroll
    for (int k = 0; k < 16; ++k) {
        int e = e0 + k * 256 + t;
        if (e < E) {
            int s = m ? ei[2 * e] : ei[e];
            int d = m ? ei[2 * (E + e)] : ei[E + e];
            if ((unsigned)d < (unsigned)n && (unsigned)s < (unsigned)n)
                atomicAdd(&h[d >> 8], 1);
        }
    }
    __syncthreads();
    int K = (n + 255) >> 8;
    for (int b = t; b < K; b += 256)
        if (h[b]) atomicAdd(&bcnt[b], h[b]);
}

// Exclusive scan of K (<=512) bucket counts -> bbase[0..K], partition
// cursors cur[], and row_ptr[n] (grand total).
__global__ __launch_bounds__(512) void bucket_scan_kernel(
    const int* __restrict__ bcnt, int* __restrict__ bbase,
    int* __restrict__ cur, int* __restrict__ row_ptr_n, int K) {
    __shared__ int wtot[8];
    int tid = threadIdx.x, lane = tid & 63, wv = tid >> 6;
    int v = (tid < K) ? bcnt[tid] : 0;
    int incl = v;
#pragma unroll
    for (int off = 1; off < 64; off <<= 1) {
        int t = __shfl_up(incl, off, 64);
        if (lane >= off) incl += t;
    }
    if (lane == 63) wtot[wv] = incl;
    __syncthreads();
    int wo = 0;
    for (int w = 0; w < wv; ++w) wo += wtot[w];
    int ex = wo + incl - v;
    if (tid < K) {
        bbase[tid] = ex;
        cur[tid] = ex;
    }
    if (tid == K - 1) {
        bbase[K] = ex + v;
        *row_ptr_n = ex + v;
    }
}

// Partition: LDS-histogram 4096 edges into K buckets, reserve contiguous
// ranges with one global atomic per (block,bucket), write packed pairs
// (s | (d&255)<<24) line-dense into the bucket's region.
__global__ __launch_bounds__(256) void partition_kernel(
    const int* __restrict__ ei, int E, int n, const int* __restrict__ mode,
    int* __restrict__ cur, unsigned* __restrict__ pairs) {
    __shared__ int hist[512];
    __shared__ int base[512];
    int t = threadIdx.x;
    for (int i = t; i < 512; i += 256) hist[i] = 0;
    __syncthreads();
    int m = *mode;
    int e0 = blockIdx.x * 4096;
    int s_[16], d_[16], o_[16];
#pragma unroll
    for (int k = 0; k < 16; ++k) {
        int e = e0 + k * 256 + t;
        d_[k] = -1;
        if (e < E) {
            int s = m ? ei[2 * e] : ei[e];
            int d = m ? ei[2 * (E + e)] : ei[E + e];
            if ((unsigned)d < (unsigned)n && (unsigned)s < (unsigned)n) {
                s_[k] = s;
                d_[k] = d;
                o_[k] = atomicAdd(&hist[d >> 8], 1);
            }
        }
    }
    __syncthreads();
    int K = (n + 255) >> 8;
    for (int b = t; b < K; b += 256) {
        int h = hist[b];
        base[b] = h ? atomicAdd(&cur[b], h) : 0;
    }
    __syncthreads();
#pragma unroll
    for (int k = 0; k < 16; ++k) {
        if (d_[k] >= 0) {
            int b = d_[k] >> 8;
            unsigned p = (unsigned)s_[k] | ((unsigned)(d_[k] & 255) << 24);
            pairs[(size_t)(base[b] + o_[k])] = p;
        }
    }
}

// Fused CSR build, one block per bucket: LDS histogram of the bucket's
// packed pairs -> LDS scan -> row_ptr + dinv for the 256-node range, then
// place csr_src via LDS cursors. All global windows L2-local.
__global__ __launch_bounds__(256) void build_kernel(
    const unsigned* __restrict__ pairs, const int* __restrict__ bbase,
    int* __restrict__ row_ptr, float* __restrict__ dinv,
    int* __restrict__ csr_src, int n) {
    __shared__ int hist[256];
    __shared__ int wtot[4];
    int b = blockIdx.x;
    int lo = b << 8;
    int beg = bbase[b], end = bbase[b + 1];
    int tid = threadIdx.x, lane = tid & 63, wv = tid >> 6;
    hist[tid] = 0;
    __syncthreads();
    for (int i = beg + tid; i < end; i += 256)
        atomicAdd(&hist[pairs[i] >> 24], 1);
    __syncthreads();
    int v = hist[tid];
    int incl = v;
#pragma unroll
    for (int off = 1; off < 64; off <<= 1) {
        int t = __shfl_up(incl, off, 64);
        if (lane >= off) incl += t;
    }
    if (lane == 63) wtot[wv] = incl;
    __syncthreads();
    int wo = 0;
    for (int w = 0; w < wv; ++w) wo += wtot[w];
    int ex = wo + incl - v;   // exclusive scan within bucket
    int node = lo + tid;
    if (node < n) {
        row_ptr[node] = beg + ex;
        dinv[node] = rsqrtf((float)(v + 1));   // +1 self-loop
    }
    __syncthreads();
    hist[tid] = ex;   // reuse as cursor
    __syncthreads();
    for (int i = beg + tid; i < end; i += 256) {
        unsigned p = pairs[i];
        int pos = atomicAdd(&hist[p >> 24], 1);
        csr_src[beg + pos] = (int)(p & 0x00FFFFFFu);
    }
}

// ---------------------------------------------------------------------------
// Half-width aggregation over one 64-col slab S [n][64] fp16 (128B rows).
// One wave per node. Two 32-lane groups (g = lane>>5) process two different
// edges per step: each group's gather = one full cache line. Cross-half
// reduction via shfl_xor(32). out = di*(di*S[i] + sum_e dinv[s]*S[s]) + bias.
// MODE 0: relu, fp16 slab out. MODE 1: f32 slab out [n x 64].
// ---------------------------------------------------------------------------
template <int MODE>
__global__ __launch_bounds__(256) void agg_half_kernel(
    const __half* __restrict__ S, const float* __restrict__ dinv,
    const int* __restrict__ row_ptr, const int* __restrict__ csr_src,
    const float* __restrict__ bias, void* __restrict__ outp, int n) {
    int wave = (int)((blockIdx.x * blockDim.x + threadIdx.x) >> 6);
    int lane = threadIdx.x & 63;
    if (wave >= n) return;
    int g = lane >> 5;
    int c = lane & 31;                      // half2 col within slab
    const __half2* x2 = (const __half2*)S;
    float di = dinv[wave];
    float2 self = __half22float2(x2[(size_t)wave * 32 + c]);
    float ax = 0.f, ay = 0.f;
    int e = row_ptr[wave], end = row_ptr[wave + 1];
    for (; e + 8 <= end; e += 8) {
        int s[4];
        float w[4];
        float2 u[4];
#pragma unroll
        for (int k = 0; k < 4; ++k)
            s[k] = __builtin_nontemporal_load(csr_src + e + 2 * k + g);
#pragma unroll
        for (int k = 0; k < 4; ++k)
            u[k] = __half22float2(x2[(size_t)s[k] * 32 + c]);
#pragma unroll
        for (int k = 0; k < 4; ++k) w[k] = dinv[s[k]];
#pragma unroll
        for (int k = 0; k < 4; ++k) {
            ax += w[k] * u[k].x;
            ay += w[k] * u[k].y;
        }
    }
    for (; e + 2 <= end; e += 2) {
        int s = __builtin_nontemporal_load(csr_src + e + g);
        float w = dinv[s];
        float2 u = __half22float2(x2[(size_t)s * 32 + c]);
        ax += w * u.x;
        ay += w * u.y;
    }
    if (e < end) {
        int s = __builtin_nontemporal_load(csr_src + e);
        float w = g ? 0.f : dinv[s];        // only group 0 contributes
        float2 u = __half22float2(x2[(size_t)s * 32 + c]);
        ax += w * u.x;
        ay += w * u.y;
    }
    ax += __shfl_xor(ax, 32);
    ay += __shfl_xor(ay, 32);
    if (lane < 32) {
        float2 bv = *(const float2*)(bias + 2 * c);
        float vx = di * (di * self.x + ax) + bv.x;
        float vy = di * (di * self.y + ay) + bv.y;
        if (MODE == 0) {
            vx = fmaxf(vx, 0.f);
            vy = fmaxf(vy, 0.f);
            __half2 hv = __floats2half2_rn(vx, vy);
            unsigned int bits;
            __builtin_memcpy(&bits, &hv, 4);
            unsigned int* o = (unsigned int*)outp;
            __builtin_nontemporal_store(bits, o + (size_t)wave * 32 + c);
        } else {
            f32x2 v = {vx, vy};
            float* o = (float*)outp;
            __builtin_nontemporal_store(v, (f32x2*)(o + (size_t)wave * 64 + 2 * c));
        }
    }
}

// ---------------------------------------------------------------------------
// Pack f32 weights into fp16 MFMA B-fragment order.
// b_frag for (nt,kt) at lane l holds B[k][c], k = kt*32+(l>>4)*8+e,
// c = nt*16+(l&15). Wb==nullptr: single 128-col Wa (ld 128);
// else cols 0..63 from Wa, 64..127 from Wb (each ld 64).
// ---------------------------------------------------------------------------
__global__ void packw_kernel(const float* __restrict__ Wa,
                             const float* __restrict__ Wb,
                             __half* __restrict__ dst) {
    int t = blockIdx.x * 256 + threadIdx.x;   // 0..2047
    int lane = t & 63;
    int fk = t >> 6;          // nt*4 + kt
    int kt = fk & 3, nt = fk >> 2;
    int k0 = kt * 32 + ((lane >> 4) << 3);
    int c = nt * 16 + (lane & 15);
    const float* W;
    int ldw, cc;
    if (Wb) {
        W = (c < 64) ? Wa : Wb;
        cc = c & 63;
        ldw = 64;
    } else {
        W = Wa;
        cc = c;
        ldw = 128;
    }
    __half tmp[8];
#pragma unroll
    for (int e = 0; e < 8; ++e)
        tmp[e] = __float2half(W[(size_t)(k0 + e) * ldw + cc]);
    *(float4*)(dst + (size_t)t * 8) = *(float4*)tmp;
}

// ---------------------------------------------------------------------------
// MFMA GEMM 1: A [n x 128] f32 row-major @ packed Wp -> two fp16 slabs
// o0,o1 [n][64] (cols 0..63 / 64..127). 4 waves/block, 16-row strip/wave.
// A-frag: lane holds row (lane&15), k = kt*32+(lane>>4)*8+e
// C-frag: col = lane&15, row = (lane>>4)*4 + reg   (m89-verified)
// ---------------------------------------------------------------------------
__global__ __launch_bounds__(256) void gemm_f32_kernel(
    const float* __restrict__ A, const __half* __restrict__ Wp,
    __half* __restrict__ o0, __half* __restrict__ o1, int n) {
    int lane = threadIdx.x & 63;
    int wv = threadIdx.x >> 6;
    int m0 = (blockIdx.x * 4 + wv) * 16;
    if (m0 >= n) return;
    int row_a = m0 + (lane & 15);
    if (row_a >= n) row_a = n - 1;
    half8 afr[4];
    const float4* Arow = (const float4*)(A + (size_t)row_a * 128);
#pragma unroll
    for (int kt = 0; kt < 4; ++kt) {
        float4 lo = Arow[kt * 8 + ((lane >> 4) << 1)];
        float4 hi = Arow[kt * 8 + ((lane >> 4) << 1) + 1];
        half8 h;
        h[0] = (_Float16)lo.x; h[1] = (_Float16)lo.y;
        h[2] = (_Float16)lo.z; h[3] = (_Float16)lo.w;
        h[4] = (_Float16)hi.x; h[5] = (_Float16)hi.y;
        h[6] = (_Float16)hi.z; h[7] = (_Float16)hi.w;
        afr[kt] = h;
    }
    const half8* Wf = (const half8*)Wp;
    int colw = lane & 15;
    int rbase = m0 + ((lane >> 4) << 2);
#pragma unroll
    for (int nt = 0; nt < 8; ++nt) {
        f32x4 acc = {0.f, 0.f, 0.f, 0.f};
#pragma unroll
        for (int kt = 0; kt < 4; ++kt)
            acc = __builtin_amdgcn_mfma_f32_16x16x32_f16(
                afr[kt], Wf[(nt * 4 + kt) * 64 + lane], acc, 0, 0, 0);
        __half* o = (nt < 4) ? o0 : o1;
        int c = (nt & 3) * 16 + colw;
#pragma unroll
        for (int e = 0; e < 4; ++e) {
            int r = rbase + e;
            if (r < n) o[(size_t)r * 64 + c] = __float2half(acc[e]);
        }
    }
}

// ---------------------------------------------------------------------------
// MFMA GEMM 2: A from two fp16 slabs A0,A1 [n][64] @ packed Wp -> two fp16
// slabs o0,o1. Same fragment layout; A-frag k<64 from A0, k>=64 from A1.
// ---------------------------------------------------------------------------
__global__ __launch_bounds__(256) void gemm_h16_kernel(
    const __half* __restrict__ A0, const __half* __restrict__ A1,
    const __half* __restrict__ Wp,
    __half* __restrict__ o0, __half* __restrict__ o1, int n) {
    int lane = threadIdx.x & 63;
    int wv = threadIdx.x >> 6;
    int m0 = (blockIdx.x * 4 + wv) * 16;
    if (m0 >= n) return;
    int row_a = m0 + (lane & 15);
    if (row_a >= n) row_a = n - 1;
    half8 afr[4];
#pragma unroll
    for (int kt = 0; kt < 4; ++kt) {
        const __half* Ap = (kt < 2) ? A0 : A1;
        int cc = (kt & 1) * 32 + ((lane >> 4) << 3);
        afr[kt] = *(const half8*)(Ap + (size_t)row_a * 64 + cc);
    }
    const half8* Wf = (const half8*)Wp;
    int colw = lane & 15;
    int rbase = m0 + ((lane >> 4) << 2);
#pragma unroll
    for (int nt = 0; nt < 8; ++nt) {
        f32x4 acc = {0.f, 0.f, 0.f, 0.f};
#pragma unroll
        for (int kt = 0; kt < 4; ++kt)
            acc = __builtin_amdgcn_mfma_f32_16x16x32_f16(
                afr[kt], Wf[(nt * 4 + kt) * 64 + lane], acc, 0, 0, 0);
        __half* o = (nt < 4) ? o0 : o1;
        int c = (nt & 3) * 16 + colw;
#pragma unroll
        for (int e = 0; e < 4; ++e) {
            int r = rbase + e;
            if (r < n) o[(size_t)r * 64 + c] = __float2half(acc[e]);
        }
    }
}

extern "C" void kernel_launch(void* const* d_in, const int* in_sizes, int n_in,
                              void* d_out, int out_size, void* d_ws, size_t ws_size,
                              hipStream_t stream) {
    const float* x   = (const float*)d_in[0];
    const int*   ei  = (const int*)d_in[1];
    const float* W1  = (const float*)d_in[2];
    const float* b1  = (const float*)d_in[3];
    const float* Wmu = (const float*)d_in[4];
    const float* bmu = (const float*)d_in[5];
    const float* Wlv = (const float*)d_in[6];
    const float* blv = (const float*)d_in[7];
    float* out = (float*)d_out;

    const int n = in_sizes[0] / 128;   // 100000
    const int E = in_sizes[1] / 2;     // 1600000
    const int K = (n + 255) >> 8;      // dst buckets (391, <=512)

    char* ws = (char*)d_ws;
    size_t off = 0;
    auto alloc = [&](size_t bytes) -> void* {
        void* p = ws + off;
        off += (bytes + 255) & ~(size_t)255;
        return p;
    };
    int*      mode    = (int*)alloc(256);
    int*      bcnt    = (int*)alloc((size_t)K * 4);
    int*      bbase   = (int*)alloc((size_t)(K + 1) * 4);
    int*      bcur    = (int*)alloc((size_t)K * 4);
    int*      row_ptr = (int*)alloc((size_t)(n + 1) * 4);
    float*    dinv    = (float*)alloc((size_t)n * 4);
    int*      csr_src = (int*)alloc((size_t)E * 4);
    unsigned* pairs   = (unsigned*)alloc((size_t)E * 4);
    __half*   T0      = (__half*)alloc((size_t)n * 64 * 2);  // t/g cols 0..63
    __half*   T1      = (__half*)alloc((size_t)n * 64 * 2);  // t/g cols 64..127
    __half*   H0      = (__half*)alloc((size_t)n * 64 * 2);  // h cols 0..63
    __half*   H1      = (__half*)alloc((size_t)n * 64 * 2);  // h cols 64..127
    __half*   W1p     = (__half*)alloc(128 * 128 * 2);       // packed W1
    __half*   W2p     = (__half*)alloc(128 * 128 * 2);       // packed [Wmu|Wlv]

    hipMemsetAsync(bcnt, 0, (size_t)K * 4, stream);

    detect_kernel<<<1, 64, 0, stream>>>(ei, mode);

    int pb = (E + 4095) / 4096;
    bucket_count_kernel<<<pb, 256, 0, stream>>>(ei, E, n, mode, bcnt);
    bucket_scan_kernel<<<1, 512, 0, stream>>>(bcnt, bbase, bcur,
                                              row_ptr + n, K);
    partition_kernel<<<pb, 256, 0, stream>>>(ei, E, n, mode, bcur, pairs);
    build_kernel<<<K, 256, 0, stream>>>(pairs, bbase, row_ptr, dinv,
                                        csr_src, n);

    // Weight packing (tiny)
    packw_kernel<<<8, 256, 0, stream>>>(W1, nullptr, W1p);
    packw_kernel<<<8, 256, 0, stream>>>(Wmu, Wlv, W2p);

    int gb = (n + 63) / 64;        // MFMA gemm blocks
    int ab = (n + 3) / 4;          // agg: 4 waves/block, 1 wave/node

    // t = x @ W1  -> slabs T0,T1
    gemm_f32_kernel<<<gb, 256, 0, stream>>>(x, W1p, T0, T1, n);
    // h = relu(agg(t) + b1), half at a time (L2-resident 12.8MB slab each)
    agg_half_kernel<0><<<ab, 256, 0, stream>>>(T0, dinv, row_ptr, csr_src,
                                               b1, H0, n);
    agg_half_kernel<0><<<ab, 256, 0, stream>>>(T1, dinv, row_ptr, csr_src,
                                               b1 + 64, H1, n);
    // g = h @ [Wmu|Wlv] -> slabs T0 (mu-side), T1 (lv-side)
    gemm_h16_kernel<<<gb, 256, 0, stream>>>(H0, H1, W2p, T0, T1, n);
    // mu = agg(g0) + bmu ; logvar = agg(g1) + blv  (f32 slabs)
    agg_half_kernel<1><<<ab, 256, 0, stream>>>(T0, dinv, row_ptr, csr_src,
                                               bmu, out, n);
    agg_half_kernel<1><<<ab, 256, 0, stream>>>(T1, dinv, row_ptr, csr_src,
                                               blv, out + (size_t)n * 64, n);
}

// Round 12
// 244.191 us; speedup vs baseline: 1.4907x; 1.4907x over previous
//
#include <hip/hip_runtime.h>
#include <hip/hip_fp16.h>

// ---------------------------------------------------------------------------
// VGAE encoder: two GCN propagations + dense transforms.
// Transform-first: t = x@W1, h = relu(agg(t)+b1), g = h@[Wmu|Wlv],
// [mu|lv] = agg(g)+bias  (agg commutes with the right-multiply).
// agg is MONOLITHIC row-gather (256B fp16 rows, 2 cache lines/edge):
//  - column-chunked variants die on L1 line-request rate (32B/row-request)
//  - 64-col slab split (12.8MB) barely moves L2 hit rate; r10 form is the
//    empirical floor (~2.5 TB/s L2-miss-path service).
// CSR build: FIXED-CAPACITY buckets (CAP=8192 >> mean 4096) remove the
// global prefix scan entirely: partition reserves via one atomic per
// (block,bucket) on zeroed counters; per-node bounds stored as int2.
// ---------------------------------------------------------------------------

using half8 = __attribute__((ext_vector_type(8))) _Float16;
using f32x4 = __attribute__((ext_vector_type(4))) float;
using f32x2 = __attribute__((ext_vector_type(2))) float;

constexpr int CAP = 8192;   // per-bucket edge capacity (mean 4096, +64 sigma)

// Detect whether edge_index arrived as int64 (odd int32 words all zero) or
// int32. Wave-parallel. Writes mode=1 for int64, 0 for int32.
__global__ void detect_kernel(const int* __restrict__ ei, int* __restrict__ mode) {
    int lane = threadIdx.x & 63;
    int any = 0;
    for (int k = lane; k < 1024; k += 64) any |= ei[2 * k + 1];
    unsigned long long b = __ballot(any != 0);
    if (threadIdx.x == 0) *mode = (b == 0ull) ? 1 : 0;
}

// Partition: LDS-histogram 4096 edges into K dst-buckets (256 nodes each),
// reserve ranges with one global atomic per (block,bucket) on zeroed bcnt,
// write packed pairs (s | (d&255)<<24) into the bucket's fixed-cap region.
__global__ __launch_bounds__(256) void partition_kernel(
    const int* __restrict__ ei, int E, int n, const int* __restrict__ mode,
    int* __restrict__ bcnt, unsigned* __restrict__ pairs) {
    __shared__ int hist[512];
    __shared__ int base[512];
    int t = threadIdx.x;
    for (int i = t; i < 512; i += 256) hist[i] = 0;
    __syncthreads();
    int m = *mode;
    int e0 = blockIdx.x * 4096;
    int s_[16], d_[16], o_[16];
#pragma unroll
    for (int k = 0; k < 16; ++k) {
        int e = e0 + k * 256 + t;
        d_[k] = -1;
        if (e < E) {
            int s = m ? ei[2 * e] : ei[e];
            int d = m ? ei[2 * (E + e)] : ei[E + e];
            if ((unsigned)d < (unsigned)n && (unsigned)s < (unsigned)n) {
                s_[k] = s;
                d_[k] = d;
                o_[k] = atomicAdd(&hist[d >> 8], 1);
            }
        }
    }
    __syncthreads();
    int K = (n + 255) >> 8;
    for (int b = t; b < K; b += 256) {
        int h = hist[b];
        base[b] = h ? atomicAdd(&bcnt[b], h) : 0;
    }
    __syncthreads();
#pragma unroll
    for (int k = 0; k < 16; ++k) {
        if (d_[k] >= 0) {
            int b = d_[k] >> 8;
            unsigned p = (unsigned)s_[k] | ((unsigned)(d_[k] & 255) << 24);
            pairs[(size_t)b * CAP + base[b] + o_[k]] = p;
        }
    }
}

// Fused CSR build, one block per bucket: LDS histogram of the bucket's
// packed pairs -> LDS scan -> per-node int2 bounds + dinv, then place
// csr_src via LDS cursors. All global windows (32KB pairs, 32KB csr,
// 2KB rowbe/dinv) are L2-local. No global prefix scan needed.
__global__ __launch_bounds__(256) void build_kernel(
    const unsigned* __restrict__ pairs, const int* __restrict__ bcnt,
    int2* __restrict__ rowbe, float* __restrict__ dinv,
    int* __restrict__ csr_src, int n) {
    __shared__ int hist[256];
    __shared__ int wtot[4];
    int b = blockIdx.x;
    int cnt = bcnt[b];
    size_t gbase = (size_t)b * CAP;
    int tid = threadIdx.x, lane = tid & 63, wv = tid >> 6;
    hist[tid] = 0;
    __syncthreads();
    for (int i = tid; i < cnt; i += 256)
        atomicAdd(&hist[pairs[gbase + i] >> 24], 1);
    __syncthreads();
    int v = hist[tid];
    int incl = v;
#pragma unroll
    for (int off = 1; off < 64; off <<= 1) {
        int t = __shfl_up(incl, off, 64);
        if (lane >= off) incl += t;
    }
    if (lane == 63) wtot[wv] = incl;
    __syncthreads();
    int wo = 0;
    for (int w = 0; w < wv; ++w) wo += wtot[w];
    int ex = wo + incl - v;   // exclusive scan within bucket
    int node = (b << 8) + tid;
    if (node < n) {
        int beg = (int)gbase + ex;
        rowbe[node] = make_int2(beg, beg + v);
        dinv[node] = rsqrtf((float)(v + 1));   // +1 self-loop
    }
    __syncthreads();
    hist[tid] = ex;   // reuse as cursor
    __syncthreads();
    for (int i = tid; i < cnt; i += 256) {
        unsigned p = pairs[gbase + i];
        int pos = atomicAdd(&hist[p >> 24], 1);
        csr_src[gbase + pos] = (int)(p & 0x00FFFFFFu);
    }
}

// ---------------------------------------------------------------------------
// Monolithic row-gather aggregation (one wave per node, lane = half2 col).
// Wave-uniform src index via readfirstlane (scalar dinv load), 8-deep
// unroll for MLP. out = di*(di*T[i] + sum_e dinv[s]*T[s]) + bias.
// Bias: lane<32 -> biasa[2*lane..], lane>=32 -> biasb[(2*lane)&63..].
// MODE 0: relu, fp16 row-major out (h). MODE 1: f32 split slabs (mu | lv).
// ---------------------------------------------------------------------------
template <int MODE>
__global__ __launch_bounds__(256) void agg_row_kernel(
    const __half* __restrict__ T, const float* __restrict__ dinv,
    const int2* __restrict__ rowbe, const int* __restrict__ csr_src,
    const float* __restrict__ biasa, const float* __restrict__ biasb,
    void* __restrict__ outa, void* __restrict__ outb, int n) {
    int wave = (int)((blockIdx.x * blockDim.x + threadIdx.x) >> 6);
    int lane = threadIdx.x & 63;
    if (wave >= n) return;
    const __half2* x2 = (const __half2*)T;
    float di = dinv[wave];
    float2 xf = __half22float2(x2[((size_t)wave << 6) + lane]);
    float ax = 0.f, ay = 0.f;
    int2 be = rowbe[wave];
    int e = be.x, end = be.y;
    for (; e + 8 <= end; e += 8) {
        int s[8];
        float w[8];
        float2 u[8];
#pragma unroll
        for (int k = 0; k < 8; ++k)
            s[k] = __builtin_amdgcn_readfirstlane(csr_src[e + k]);
#pragma unroll
        for (int k = 0; k < 8; ++k) w[k] = dinv[s[k]];
#pragma unroll
        for (int k = 0; k < 8; ++k)
            u[k] = __half22float2(x2[((size_t)s[k] << 6) + lane]);
#pragma unroll
        for (int k = 0; k < 8; ++k) {
            ax += w[k] * u[k].x;
            ay += w[k] * u[k].y;
        }
    }
    for (; e < end; ++e) {
        int s = __builtin_amdgcn_readfirstlane(csr_src[e]);
        float w = dinv[s];
        float2 u = __half22float2(x2[((size_t)s << 6) + lane]);
        ax += w * u.x;
        ay += w * u.y;
    }
    const float* bp = (lane < 32) ? biasa : biasb;
    float2 bv = *(const float2*)(bp + ((2 * lane) & 63));
    float vx = di * (di * xf.x + ax) + bv.x;
    float vy = di * (di * xf.y + ay) + bv.y;
    if (MODE == 0) {
        vx = fmaxf(vx, 0.f);
        vy = fmaxf(vy, 0.f);
        __half2 hv = __floats2half2_rn(vx, vy);
        unsigned int bits;
        __builtin_memcpy(&bits, &hv, 4);
        unsigned int* o = (unsigned int*)outa;
        __builtin_nontemporal_store(bits, o + ((size_t)wave << 6) + lane);
    } else {
        // cols 2*lane, 2*lane+1: lane<32 -> mu slab, lane>=32 -> lv slab
        float* o = (lane < 32) ? (float*)outa : (float*)outb;
        int cc = (2 * lane) & 63;
        f32x2 v = {vx, vy};
        __builtin_nontemporal_store(v, (f32x2*)(o + (size_t)wave * 64 + cc));
    }
}

// ---------------------------------------------------------------------------
// Pack f32 weights into fp16 MFMA B-fragment order.
// b_frag for (nt,kt) at lane l holds B[k][c], k = kt*32+(l>>4)*8+e,
// c = nt*16+(l&15). Wb==nullptr: single 128-col Wa (ld 128);
// else cols 0..63 from Wa, 64..127 from Wb (each ld 64).
// ---------------------------------------------------------------------------
__global__ void packw_kernel(const float* __restrict__ Wa,
                             const float* __restrict__ Wb,
                             __half* __restrict__ dst) {
    int t = blockIdx.x * 256 + threadIdx.x;   // 0..2047
    int lane = t & 63;
    int fk = t >> 6;          // nt*4 + kt
    int kt = fk & 3, nt = fk >> 2;
    int k0 = kt * 32 + ((lane >> 4) << 3);
    int c = nt * 16 + (lane & 15);
    const float* W;
    int ldw, cc;
    if (Wb) {
        W = (c < 64) ? Wa : Wb;
        cc = c & 63;
        ldw = 64;
    } else {
        W = Wa;
        cc = c;
        ldw = 128;
    }
    __half tmp[8];
#pragma unroll
    for (int e = 0; e < 8; ++e)
        tmp[e] = __float2half(W[(size_t)(k0 + e) * ldw + cc]);
    *(float4*)(dst + (size_t)t * 8) = *(float4*)tmp;
}

// ---------------------------------------------------------------------------
// Pure MFMA GEMM (no bias/relu): A [n x 128] (f32 or fp16 row-major) @
// packed Wp -> fp16 row-major out. 4 waves/block, 16-row strip per wave.
// A-frag: lane holds row (lane&15), k = kt*32+(lane>>4)*8+e
// C-frag: col = lane&15, row = (lane>>4)*4 + reg   (m89-verified)
// ---------------------------------------------------------------------------
template <typename AT>
__global__ __launch_bounds__(256) void gemm_pure_kernel(
    const AT* __restrict__ A, const __half* __restrict__ Wp,
    __half* __restrict__ outh, int n) {
    int lane = threadIdx.x & 63;
    int wv = threadIdx.x >> 6;
    int m0 = (blockIdx.x * 4 + wv) * 16;
    if (m0 >= n) return;
    int row_a = m0 + (lane & 15);
    if (row_a >= n) row_a = n - 1;              // clamp; stores guarded
    half8 afr[4];
    if constexpr (sizeof(AT) == 4) {
        const float4* Arow = (const float4*)(A + (size_t)row_a * 128);
#pragma unroll
        for (int kt = 0; kt < 4; ++kt) {
            float4 lo = Arow[kt * 8 + ((lane >> 4) << 1)];
            float4 hi = Arow[kt * 8 + ((lane >> 4) << 1) + 1];
            half8 h;
            h[0] = (_Float16)lo.x; h[1] = (_Float16)lo.y;
            h[2] = (_Float16)lo.z; h[3] = (_Float16)lo.w;
            h[4] = (_Float16)hi.x; h[5] = (_Float16)hi.y;
            h[6] = (_Float16)hi.z; h[7] = (_Float16)hi.w;
            afr[kt] = h;
        }
    } else {
        const half8* Arow = (const half8*)(A + (size_t)row_a * 128);
#pragma unroll
        for (int kt = 0; kt < 4; ++kt) afr[kt] = Arow[kt * 4 + (lane >> 4)];
    }

    const half8* Wf = (const half8*)Wp;
    int colw = lane & 15;
    int rbase = m0 + ((lane >> 4) << 2);

#pragma unroll
    for (int nt = 0; nt < 8; ++nt) {
        f32x4 acc = {0.f, 0.f, 0.f, 0.f};
#pragma unroll
        for (int kt = 0; kt < 4; ++kt)
            acc = __builtin_amdgcn_mfma_f32_16x16x32_f16(
                afr[kt], Wf[(nt * 4 + kt) * 64 + lane], acc, 0, 0, 0);
        int c = nt * 16 + colw;
#pragma unroll
        for (int e = 0; e < 4; ++e) {
            int r = rbase + e;
            if (r < n) outh[(size_t)r * 128 + c] = __float2half(acc[e]);
        }
    }
}

extern "C" void kernel_launch(void* const* d_in, const int* in_sizes, int n_in,
                              void* d_out, int out_size, void* d_ws, size_t ws_size,
                              hipStream_t stream) {
    const float* x   = (const float*)d_in[0];
    const int*   ei  = (const int*)d_in[1];
    const float* W1  = (const float*)d_in[2];
    const float* b1  = (const float*)d_in[3];
    const float* Wmu = (const float*)d_in[4];
    const float* bmu = (const float*)d_in[5];
    const float* Wlv = (const float*)d_in[6];
    const float* blv = (const float*)d_in[7];
    float* out = (float*)d_out;

    const int n = in_sizes[0] / 128;   // 100000
    const int E = in_sizes[1] / 2;     // 1600000
    const int K = (n + 255) >> 8;      // dst buckets (391, <=512)

    char* ws = (char*)d_ws;
    size_t off = 0;
    auto alloc = [&](size_t bytes) -> void* {
        void* p = ws + off;
        off += (bytes + 255) & ~(size_t)255;
        return p;
    };
    int*      mode    = (int*)alloc(256);
    int*      bcnt    = (int*)alloc((size_t)K * 4);
    int2*     rowbe   = (int2*)alloc((size_t)n * 8);
    float*    dinv    = (float*)alloc((size_t)n * 4);
    int*      csr_src = (int*)alloc((size_t)K * CAP * 4);
    unsigned* pairs   = (unsigned*)alloc((size_t)K * CAP * 4);
    __half*   bufT    = (__half*)alloc((size_t)n * 128 * 2);  // t, then g
    __half*   bufH    = (__half*)alloc((size_t)n * 128 * 2);  // h
    __half*   W1p     = (__half*)alloc(128 * 128 * 2);        // packed W1
    __half*   W2p     = (__half*)alloc(128 * 128 * 2);        // packed [Wmu|Wlv]

    hipMemsetAsync(bcnt, 0, (size_t)K * 4, stream);

    detect_kernel<<<1, 64, 0, stream>>>(ei, mode);

    int pb = (E + 4095) / 4096;
    partition_kernel<<<pb, 256, 0, stream>>>(ei, E, n, mode, bcnt, pairs);
    build_kernel<<<K, 256, 0, stream>>>(pairs, bcnt, rowbe, dinv, csr_src, n);

    // Weight packing (tiny)
    packw_kernel<<<8, 256, 0, stream>>>(W1, nullptr, W1p);
    packw_kernel<<<8, 256, 0, stream>>>(Wmu, Wlv, W2p);

    int gb = (n + 63) / 64;        // MFMA gemm blocks
    int ab = (n + 3) / 4;          // agg: 4 waves/block, 1 wave/node

    // t = x @ W1  (f32 A -> fp16 row-major)
    gemm_pure_kernel<float><<<gb, 256, 0, stream>>>(x, W1p, bufT, n);
    // h = relu(agg(t) + b1)
    agg_row_kernel<0><<<ab, 256, 0, stream>>>(bufT, dinv, rowbe, csr_src,
                                              b1, b1 + 64, bufH, nullptr, n);
    // g = h @ [Wmu|Wlv]
    gemm_pure_kernel<__half><<<gb, 256, 0, stream>>>(bufH, W2p, bufT, n);
    // mu / logvar = agg(g) + bias  (f32 slabs)
    agg_row_kernel<1><<<ab, 256, 0, stream>>>(bufT, dinv, rowbe, csr_src,
                                              bmu, blv, out,
                                              out + (size_t)n * 64, n);
}

// Round 13
// 239.580 us; speedup vs baseline: 1.5194x; 1.0192x over previous
//
#include <hip/hip_runtime.h>
#include <hip/hip_fp16.h>

// ---------------------------------------------------------------------------
// VGAE encoder: two GCN propagations + dense transforms.
// Transform-first: t = x@W1, h = relu(agg(t)+b1), g = h@[Wmu|Wlv],
// [mu|lv] = agg(g)+bias  (agg commutes with the right-multiply).
// agg is MONOLITHIC row-gather (256B fp16 rows, 2 cache lines/edge):
//  - column-chunked variants die on L1 line-request rate (32B/row-request)
//  - 64-col slab split (12.8MB) barely moves L2 hit rate; this form is the
//    empirical floor (~2.5-3.2 TB/s L2-miss-path service, VALU ~50%/SIMD).
// CSR build: FIXED-CAPACITY buckets (CAP=8192 >> mean 4096) remove the
// global prefix scan entirely: partition reserves via one atomic per
// (block,bucket) on zeroed counters; per-node bounds stored as int2.
// ---------------------------------------------------------------------------

using half8 = __attribute__((ext_vector_type(8))) _Float16;
using f32x4 = __attribute__((ext_vector_type(4))) float;
using f32x2 = __attribute__((ext_vector_type(2))) float;

constexpr int CAP = 8192;   // per-bucket edge capacity (mean 4096, +64 sigma)

// Detect int64 vs int32 edge_index (odd int32 words all zero => int64),
// and zero the bucket counters (fused to save a memset launch).
__global__ void detect_kernel(const int* __restrict__ ei, int* __restrict__ mode,
                              int* __restrict__ bcnt, int K) {
    int lane = threadIdx.x & 63;
    for (int i = lane; i < K; i += 64) bcnt[i] = 0;
    int any = 0;
    for (int k = lane; k < 1024; k += 64) any |= ei[2 * k + 1];
    unsigned long long b = __ballot(any != 0);
    if (threadIdx.x == 0) *mode = (b == 0ull) ? 1 : 0;
}

// Partition: LDS-histogram 8192 edges into K dst-buckets (256 nodes each),
// reserve ranges with one global atomic per (block,bucket) on zeroed bcnt,
// write packed pairs (s | (d&255)<<24) into the bucket's fixed-cap region.
__global__ __launch_bounds__(256) void partition_kernel(
    const int* __restrict__ ei, int E, int n, const int* __restrict__ mode,
    int* __restrict__ bcnt, unsigned* __restrict__ pairs) {
    __shared__ int hist[512];
    __shared__ int base[512];
    int t = threadIdx.x;
    for (int i = t; i < 512; i += 256) hist[i] = 0;
    __syncthreads();
    int m = *mode;
    int e0 = blockIdx.x * 8192;
    int s_[32], d_[32], o_[32];
#pragma unroll
    for (int k = 0; k < 32; ++k) {
        int e = e0 + k * 256 + t;
        d_[k] = -1;
        if (e < E) {
            int s = m ? ei[2 * e] : ei[e];
            int d = m ? ei[2 * (E + e)] : ei[E + e];
            if ((unsigned)d < (unsigned)n && (unsigned)s < (unsigned)n) {
                s_[k] = s;
                d_[k] = d;
                o_[k] = atomicAdd(&hist[d >> 8], 1);
            }
        }
    }
    __syncthreads();
    int K = (n + 255) >> 8;
    for (int b = t; b < K; b += 256) {
        int h = hist[b];
        base[b] = h ? atomicAdd(&bcnt[b], h) : 0;
    }
    __syncthreads();
#pragma unroll
    for (int k = 0; k < 32; ++k) {
        if (d_[k] >= 0) {
            int b = d_[k] >> 8;
            unsigned p = (unsigned)s_[k] | ((unsigned)(d_[k] & 255) << 24);
            pairs[(size_t)b * CAP + base[b] + o_[k]] = p;
        }
    }
}

// Fused CSR build, one block per bucket: LDS histogram of the bucket's
// packed pairs -> LDS scan -> per-node int2 bounds + dinv, then place
// csr_src via LDS cursors. All global windows (32KB pairs, 32KB csr,
// 2KB rowbe/dinv) are L2-local. No global prefix scan needed.
__global__ __launch_bounds__(256) void build_kernel(
    const unsigned* __restrict__ pairs, const int* __restrict__ bcnt,
    int2* __restrict__ rowbe, float* __restrict__ dinv,
    int* __restrict__ csr_src, int n) {
    __shared__ int hist[256];
    __shared__ int wtot[4];
    int b = blockIdx.x;
    int cnt = bcnt[b];
    size_t gbase = (size_t)b * CAP;
    int tid = threadIdx.x, lane = tid & 63, wv = tid >> 6;
    hist[tid] = 0;
    __syncthreads();
    for (int i = tid; i < cnt; i += 256)
        atomicAdd(&hist[pairs[gbase + i] >> 24], 1);
    __syncthreads();
    int v = hist[tid];
    int incl = v;
#pragma unroll
    for (int off = 1; off < 64; off <<= 1) {
        int t = __shfl_up(incl, off, 64);
        if (lane >= off) incl += t;
    }
    if (lane == 63) wtot[wv] = incl;
    __syncthreads();
    int wo = 0;
    for (int w = 0; w < wv; ++w) wo += wtot[w];
    int ex = wo + incl - v;   // exclusive scan within bucket
    int node = (b << 8) + tid;
    if (node < n) {
        int beg = (int)gbase + ex;
        rowbe[node] = make_int2(beg, beg + v);
        dinv[node] = rsqrtf((float)(v + 1));   // +1 self-loop
    }
    __syncthreads();
    hist[tid] = ex;   // reuse as cursor
    __syncthreads();
    for (int i = tid; i < cnt; i += 256) {
        unsigned p = pairs[gbase + i];
        int pos = atomicAdd(&hist[p >> 24], 1);
        csr_src[gbase + pos] = (int)(p & 0x00FFFFFFu);
    }
}

// ---------------------------------------------------------------------------
// Monolithic row-gather aggregation (one wave per node, lane = half2 col).
// Wave-uniform src index via readfirstlane (scalar dinv load), 8-deep
// unroll for MLP. out = di*(di*T[i] + sum_e dinv[s]*T[s]) + bias.
// Bias: lane<32 -> biasa[2*lane..], lane>=32 -> biasb[(2*lane)&63..].
// MODE 0: relu, fp16 row-major out (h). MODE 1: f32 split slabs (mu | lv).
// ---------------------------------------------------------------------------
template <int MODE>
__global__ __launch_bounds__(256) void agg_row_kernel(
    const __half* __restrict__ T, const float* __restrict__ dinv,
    const int2* __restrict__ rowbe, const int* __restrict__ csr_src,
    const float* __restrict__ biasa, const float* __restrict__ biasb,
    void* __restrict__ outa, void* __restrict__ outb, int n) {
    int wave = (int)((blockIdx.x * blockDim.x + threadIdx.x) >> 6);
    int lane = threadIdx.x & 63;
    if (wave >= n) return;
    const __half2* x2 = (const __half2*)T;
    float di = dinv[wave];
    float2 xf = __half22float2(x2[((size_t)wave << 6) + lane]);
    float ax = 0.f, ay = 0.f;
    int2 be = rowbe[wave];
    int e = be.x, end = be.y;
    for (; e + 8 <= end; e += 8) {
        int s[8];
        float w[8];
        float2 u[8];
#pragma unroll
        for (int k = 0; k < 8; ++k)
            s[k] = __builtin_amdgcn_readfirstlane(csr_src[e + k]);
#pragma unroll
        for (int k = 0; k < 8; ++k) w[k] = dinv[s[k]];
#pragma unroll
        for (int k = 0; k < 8; ++k)
            u[k] = __half22float2(x2[((size_t)s[k] << 6) + lane]);
#pragma unroll
        for (int k = 0; k < 8; ++k) {
            ax += w[k] * u[k].x;
            ay += w[k] * u[k].y;
        }
    }
    for (; e < end; ++e) {
        int s = __builtin_amdgcn_readfirstlane(csr_src[e]);
        float w = dinv[s];
        float2 u = __half22float2(x2[((size_t)s << 6) + lane]);
        ax += w * u.x;
        ay += w * u.y;
    }
    const float* bp = (lane < 32) ? biasa : biasb;
    float2 bv = *(const float2*)(bp + ((2 * lane) & 63));
    float vx = di * (di * xf.x + ax) + bv.x;
    float vy = di * (di * xf.y + ay) + bv.y;
    if (MODE == 0) {
        vx = fmaxf(vx, 0.f);
        vy = fmaxf(vy, 0.f);
        __half2 hv = __floats2half2_rn(vx, vy);
        unsigned int bits;
        __builtin_memcpy(&bits, &hv, 4);
        unsigned int* o = (unsigned int*)outa;
        __builtin_nontemporal_store(bits, o + ((size_t)wave << 6) + lane);
    } else {
        // cols 2*lane, 2*lane+1: lane<32 -> mu slab, lane>=32 -> lv slab
        float* o = (lane < 32) ? (float*)outa : (float*)outb;
        int cc = (2 * lane) & 63;
        f32x2 v = {vx, vy};
        __builtin_nontemporal_store(v, (f32x2*)(o + (size_t)wave * 64 + cc));
    }
}

// ---------------------------------------------------------------------------
// Pack BOTH weight matrices into fp16 MFMA B-fragment order in one launch.
// blocks 0..7: W1 (128-col, ld 128) -> dst1. blocks 8..15: [Wmu|Wlv]
// (64+64 col) -> dst2. b_frag for (nt,kt) at lane l holds B[k][c],
// k = kt*32+(l>>4)*8+e, c = nt*16+(l&15).
// ---------------------------------------------------------------------------
__global__ void packw2_kernel(const float* __restrict__ W1,
                              const float* __restrict__ Wmu,
                              const float* __restrict__ Wlv,
                              __half* __restrict__ dst1,
                              __half* __restrict__ dst2) {
    int which = blockIdx.x >> 3;
    int t = (blockIdx.x & 7) * 256 + threadIdx.x;   // 0..2047
    int lane = t & 63;
    int fk = t >> 6;          // nt*4 + kt
    int kt = fk & 3, nt = fk >> 2;
    int k0 = kt * 32 + ((lane >> 4) << 3);
    int c = nt * 16 + (lane & 15);
    const float* W;
    __half* dst;
    int ldw, cc;
    if (which) {
        W = (c < 64) ? Wmu : Wlv;
        cc = c & 63;
        ldw = 64;
        dst = dst2;
    } else {
        W = W1;
        cc = c;
        ldw = 128;
        dst = dst1;
    }
    __half tmp[8];
#pragma unroll
    for (int e = 0; e < 8; ++e)
        tmp[e] = __float2half(W[(size_t)(k0 + e) * ldw + cc]);
    *(float4*)(dst + (size_t)t * 8) = *(float4*)tmp;
}

// ---------------------------------------------------------------------------
// Pure MFMA GEMM (no bias/relu): A [n x 128] (f32 or fp16 row-major) @
// packed Wp -> fp16 row-major out. 4 waves/block, 16-row strip per wave.
// A-frag: lane holds row (lane&15), k = kt*32+(lane>>4)*8+e
// C-frag: col = lane&15, row = (lane>>4)*4 + reg   (m89-verified)
// ---------------------------------------------------------------------------
template <typename AT>
__global__ __launch_bounds__(256) void gemm_pure_kernel(
    const AT* __restrict__ A, const __half* __restrict__ Wp,
    __half* __restrict__ outh, int n) {
    int lane = threadIdx.x & 63;
    int wv = threadIdx.x >> 6;
    int m0 = (blockIdx.x * 4 + wv) * 16;
    if (m0 >= n) return;
    int row_a = m0 + (lane & 15);
    if (row_a >= n) row_a = n - 1;              // clamp; stores guarded
    half8 afr[4];
    if constexpr (sizeof(AT) == 4) {
        const float4* Arow = (const float4*)(A + (size_t)row_a * 128);
#pragma unroll
        for (int kt = 0; kt < 4; ++kt) {
            float4 lo = Arow[kt * 8 + ((lane >> 4) << 1)];
            float4 hi = Arow[kt * 8 + ((lane >> 4) << 1) + 1];
            half8 h;
            h[0] = (_Float16)lo.x; h[1] = (_Float16)lo.y;
            h[2] = (_Float16)lo.z; h[3] = (_Float16)lo.w;
            h[4] = (_Float16)hi.x; h[5] = (_Float16)hi.y;
            h[6] = (_Float16)hi.z; h[7] = (_Float16)hi.w;
            afr[kt] = h;
        }
    } else {
        const half8* Arow = (const half8*)(A + (size_t)row_a * 128);
#pragma unroll
        for (int kt = 0; kt < 4; ++kt) afr[kt] = Arow[kt * 4 + (lane >> 4)];
    }

    const half8* Wf = (const half8*)Wp;
    int colw = lane & 15;
    int rbase = m0 + ((lane >> 4) << 2);

#pragma unroll
    for (int nt = 0; nt < 8; ++nt) {
        f32x4 acc = {0.f, 0.f, 0.f, 0.f};
#pragma unroll
        for (int kt = 0; kt < 4; ++kt)
            acc = __builtin_amdgcn_mfma_f32_16x16x32_f16(
                afr[kt], Wf[(nt * 4 + kt) * 64 + lane], acc, 0, 0, 0);
        int c = nt * 16 + colw;
#pragma unroll
        for (int e = 0; e < 4; ++e) {
            int r = rbase + e;
            if (r < n) outh[(size_t)r * 128 + c] = __float2half(acc[e]);
        }
    }
}

extern "C" void kernel_launch(void* const* d_in, const int* in_sizes, int n_in,
                              void* d_out, int out_size, void* d_ws, size_t ws_size,
                              hipStream_t stream) {
    const float* x   = (const float*)d_in[0];
    const int*   ei  = (const int*)d_in[1];
    const float* W1  = (const float*)d_in[2];
    const float* b1  = (const float*)d_in[3];
    const float* Wmu = (const float*)d_in[4];
    const float* bmu = (const float*)d_in[5];
    const float* Wlv = (const float*)d_in[6];
    const float* blv = (const float*)d_in[7];
    float* out = (float*)d_out;

    const int n = in_sizes[0] / 128;   // 100000
    const int E = in_sizes[1] / 2;     // 1600000
    const int K = (n + 255) >> 8;      // dst buckets (391, <=512)

    char* ws = (char*)d_ws;
    size_t off = 0;
    auto alloc = [&](size_t bytes) -> void* {
        void* p = ws + off;
        off += (bytes + 255) & ~(size_t)255;
        return p;
    };
    int*      mode    = (int*)alloc(256);
    int*      bcnt    = (int*)alloc((size_t)K * 4);
    int2*     rowbe   = (int2*)alloc((size_t)n * 8);
    float*    dinv    = (float*)alloc((size_t)n * 4);
    int*      csr_src = (int*)alloc((size_t)K * CAP * 4);
    unsigned* pairs   = (unsigned*)alloc((size_t)K * CAP * 4);
    __half*   bufT    = (__half*)alloc((size_t)n * 128 * 2);  // t, then g
    __half*   bufH    = (__half*)alloc((size_t)n * 128 * 2);  // h
    __half*   W1p     = (__half*)alloc(128 * 128 * 2);        // packed W1
    __half*   W2p     = (__half*)alloc(128 * 128 * 2);        // packed [Wmu|Wlv]

    detect_kernel<<<1, 64, 0, stream>>>(ei, mode, bcnt, K);

    int pb = (E + 8191) / 8192;
    partition_kernel<<<pb, 256, 0, stream>>>(ei, E, n, mode, bcnt, pairs);
    build_kernel<<<K, 256, 0, stream>>>(pairs, bcnt, rowbe, dinv, csr_src, n);

    // Weight packing (both matrices, one launch)
    packw2_kernel<<<16, 256, 0, stream>>>(W1, Wmu, Wlv, W1p, W2p);

    int gb = (n + 63) / 64;        // MFMA gemm blocks
    int ab = (n + 3) / 4;          // agg: 4 waves/block, 1 wave/node

    // t = x @ W1  (f32 A -> fp16 row-major)
    gemm_pure_kernel<float><<<gb, 256, 0, stream>>>(x, W1p, bufT, n);
    // h = relu(agg(t) + b1)
    agg_row_kernel<0><<<ab, 256, 0, stream>>>(bufT, dinv, rowbe, csr_src,
                                              b1, b1 + 64, bufH, nullptr, n);
    // g = h @ [Wmu|Wlv]
    gemm_pure_kernel<__half><<<gb, 256, 0, stream>>>(bufH, W2p, bufT, n);
    // mu / logvar = agg(g) + bias  (f32 slabs)
    agg_row_kernel<1><<<ab, 256, 0, stream>>>(bufT, dinv, rowbe, csr_src,
                                              bmu, blv, out,
                                              out + (size_t)n * 64, n);
}